// Round 3
// baseline (191.093 us; speedup 1.0000x reference)
//
#include <hip/hip_runtime.h>
#include <math.h>

// Problem dims
#define B_   512
#define F_   1024
#define H1_  512
#define H2_  256
#define OUT_ 128
#define KD_  5
#define NT_  (OUT_ * KD_)   // 640

typedef short  bf16x8 __attribute__((ext_vector_type(8)));
typedef float  f32x16 __attribute__((ext_vector_type(16)));

__device__ __forceinline__ float lrelu(float v) {
    return v >= 0.f ? v : 0.2f * v;
}

// fp32 -> bf16 round-to-nearest-even
__device__ __forceinline__ unsigned int f2bf(float f) {
    unsigned int u = __float_as_uint(f);
    return (u + 0x7fffu + ((u >> 16) & 1u)) >> 16;
}
__device__ __forceinline__ unsigned int pack2bf(float a, float b) {
    return f2bf(a) | (f2bf(b) << 16);
}

// ---------------------------------------------------------------------------
// MFMA bf16 GEMM: C[M,N] = act(A[M,K] @ B[K,N] + bias)
//   - block = 256 threads (4 waves), output tile 32x32
//   - K split across the 4 waves (wave w takes k in [i*128+32w, i*128+32w+32)),
//     partials reduced through LDS at the end -> grids stay >=128 blocks
//   - fp32 global operands converted to bf16 during LDS staging
//   - LDS tiles: As[32 rows][136 k] bf16 (pad 128->136 keeps b128 reads
//     16B-aligned, conflicts <=4-way), Bt[32 cols][136 k] bf16 (B transposed)
//   - v_mfma_f32_32x32x16_bf16: A lane m=l&31, k=(l>>5)*8+j (8 contiguous);
//     B lane n=l&31, same k pattern; C/D: col=lane&31,
//     row=(reg&3)+8*(reg>>2)+4*(lane>>5)   [verified mapping]
// Requires: M,N % 32 == 0, K % 128 == 0. (All call sites satisfy this.)
// CONCAT_A: A = concat([Ac (ld 256), A2 (ld 128)]), K = 384.
// TRANS_OUT: C[col*M + row] (produces Mt for the disc kernel).
// ---------------------------------------------------------------------------
template<bool RELU, bool HAS_BIAS, bool TRANS_OUT, bool CONCAT_A>
__global__ __launch_bounds__(256)
void gemm_mfma(const float* __restrict__ A, const float* __restrict__ A2,
               const float* __restrict__ Bg, const float* __restrict__ bias,
               float* __restrict__ C, int M, int N, int K, int lda)
{
    __shared__ unsigned char lds_raw[2 * 32 * 136 * 2];   // 17408 B
    unsigned short* As = (unsigned short*)lds_raw;         // [32][136]
    unsigned short* Bs = As + 32 * 136;                    // [32][136]
    float* Red = (float*)lds_raw;                          // 4096 f32 (aliased)

    const int tid  = threadIdx.x;
    const int wav  = tid >> 6;          // 0..3  (k-split index)
    const int lane = tid & 63;
    const int half = lane >> 5;         // k-chunk within MFMA step
    const int mrow = lane & 31;         // A row / B col within tile
    const int m0   = blockIdx.y * 32;
    const int n0   = blockIdx.x * 32;

    f32x16 acc;
    #pragma unroll
    for (int i = 0; i < 16; ++i) acc[i] = 0.f;

    const int n_iter = K >> 7;          // K/128
    for (int it = 0; it < n_iter; ++it) {
        const int kbase = it << 7;

        // ---- stage A tile: 32 rows x 128 k (fp32 -> bf16) ----
        {
            const int kk2 = tid & 63;           // k-pair 0..63
            const int mb  = tid >> 6;           // row base 0..3
            #pragma unroll
            for (int p = 0; p < 8; ++p) {
                const int m = mb + 4 * p;
                const int k = kbase + 2 * kk2;
                float vx, vy;
                if (CONCAT_A) {
                    if (k < H2_) {
                        const float2 v = *(const float2*)&A[(m0 + m) * H2_ + k];
                        vx = v.x; vy = v.y;
                    } else {
                        const float2 v = *(const float2*)&A2[(m0 + m) * OUT_ + (k - H2_)];
                        vx = v.x; vy = v.y;
                    }
                } else {
                    const float2 v = *(const float2*)&A[(m0 + m) * lda + k];
                    vx = v.x; vy = v.y;
                }
                ((unsigned int*)As)[m * 68 + kk2] = pack2bf(vx, vy);
            }
        }
        // ---- stage B tile transposed: Bt[n][k], 32 cols x 128 k ----
        {
            const int n  = tid & 31;
            const int kb = tid >> 5;            // k-pair base 0..7
            #pragma unroll
            for (int p = 0; p < 8; ++p) {
                const int kp = kb + 8 * p;      // k-pair 0..63
                const float b0v = Bg[(kbase + 2 * kp)     * N + n0 + n];
                const float b1v = Bg[(kbase + 2 * kp + 1) * N + n0 + n];
                ((unsigned int*)Bs)[n * 68 + kp] = pack2bf(b0v, b1v);
            }
        }
        __syncthreads();

        // ---- 2 MFMA steps over this wave's 32-k slice ----
        const int kloc = 32 * wav + 8 * half;
        {
            const bf16x8 af = *(const bf16x8*)&As[mrow * 136 + kloc];
            const bf16x8 bf = *(const bf16x8*)&Bs[mrow * 136 + kloc];
            acc = __builtin_amdgcn_mfma_f32_32x32x16_bf16(af, bf, acc, 0, 0, 0);
        }
        {
            const bf16x8 af = *(const bf16x8*)&As[mrow * 136 + kloc + 16];
            const bf16x8 bf = *(const bf16x8*)&Bs[mrow * 136 + kloc + 16];
            acc = __builtin_amdgcn_mfma_f32_32x32x16_bf16(af, bf, acc, 0, 0, 0);
        }
        __syncthreads();
    }

    // ---- reduce the 4 wave-partials through LDS ----
    #pragma unroll
    for (int r = 0; r < 16; ++r) {
        const int row = (r & 3) + 8 * (r >> 2) + 4 * half;   // C/D layout
        const int col = mrow;
        Red[wav * 1024 + row * 32 + col] = acc[r];
    }
    __syncthreads();

    #pragma unroll
    for (int q = 0; q < 4; ++q) {
        const int e = tid + 256 * q;               // 0..1023
        float u = Red[e] + Red[1024 + e] + Red[2048 + e] + Red[3072 + e];
        const int row = e >> 5, col = e & 31;
        if (HAS_BIAS) u += bias[n0 + col];
        if (RELU) u = lrelu(u);
        if (TRANS_OUT) C[(n0 + col) * M + (m0 + row)] = u;
        else           C[(m0 + row) * N + (n0 + col)] = u;
    }
}

// ---------------------------------------------------------------------------
// Minibatch discrimination from transposed M:
//   Mt: [640][512], row n = o*5+k holds M[:, o, k] contiguously.
//   o_b[j, o] = sum_i exp(-sum_k |Mt[o*5+k][i] - Mt[o*5+k][j]|) - 1
// ---------------------------------------------------------------------------
__global__ __launch_bounds__(256)
void minibatch_disc(const float* __restrict__ Mt, float* __restrict__ o_b) {
    __shared__ float L[KD_ * B_];
    const int o = blockIdx.x >> 1;
    const int j = (blockIdx.x & 1) * 256 + threadIdx.x;
    const float4* src = (const float4*)(Mt + o * KD_ * B_);
    float4* dst = (float4*)L;
    for (int e = threadIdx.x; e < (KD_ * B_) / 4; e += 256)
        dst[e] = src[e];
    __syncthreads();

    const float mj0 = L[0 * B_ + j], mj1 = L[1 * B_ + j], mj2 = L[2 * B_ + j],
                mj3 = L[3 * B_ + j], mj4 = L[4 * B_ + j];
    float accA = 0.f, accB = 0.f;
    #pragma unroll 4
    for (int i = 0; i < B_; i += 2) {
        {
            float n0 = fabsf(L[0 * B_ + i] - mj0) + fabsf(L[1 * B_ + i] - mj1);
            float n1 = fabsf(L[2 * B_ + i] - mj2) + fabsf(L[3 * B_ + i] - mj3);
            accA += __expf(-(n0 + n1 + fabsf(L[4 * B_ + i] - mj4)));
        }
        {
            const int i2 = i + 1;
            float n0 = fabsf(L[0 * B_ + i2] - mj0) + fabsf(L[1 * B_ + i2] - mj1);
            float n1 = fabsf(L[2 * B_ + i2] - mj2) + fabsf(L[3 * B_ + i2] - mj3);
            accB += __expf(-(n0 + n1 + fabsf(L[4 * B_ + i2] - mj4)));
        }
    }
    o_b[j * OUT_ + o] = accA + accB - 1.f;
}

// ---------------------------------------------------------------------------
// out[m] = dot(z3[m,:], W4[:,0]) + b4   (K = 128), float4 reads
// ---------------------------------------------------------------------------
__global__ void final_dot(const float* __restrict__ z3, const float* __restrict__ W4,
                          const float* __restrict__ b4, float* __restrict__ out) {
    const int m = blockIdx.x * 256 + threadIdx.x;
    const float4* zr = (const float4*)(z3 + m * OUT_);
    const float4* w  = (const float4*)W4;
    float acc = 0.f;
    #pragma unroll
    for (int k = 0; k < OUT_ / 4; ++k) {
        float4 a = zr[k], b = w[k];
        acc += a.x * b.x + a.y * b.y + a.z * b.z + a.w * b.w;
    }
    out[m] = acc + b4[0];
}

extern "C" void kernel_launch(void* const* d_in, const int* in_sizes, int n_in,
                              void* d_out, int out_size, void* d_ws, size_t ws_size,
                              hipStream_t stream) {
    const float* x  = (const float*)d_in[0];   // (512, 1024)
    const float* W1 = (const float*)d_in[1];   // (1024, 512)
    const float* b1 = (const float*)d_in[2];   // (512,)
    const float* W2 = (const float*)d_in[3];   // (512, 256)
    const float* b2 = (const float*)d_in[4];   // (256,)
    const float* T  = (const float*)d_in[5];   // (256, 640) flat
    const float* W3 = (const float*)d_in[6];   // (384, 128)
    const float* b3 = (const float*)d_in[7];   // (128,)
    const float* W4 = (const float*)d_in[8];   // (128, 1)
    const float* b4 = (const float*)d_in[9];   // (1,)
    float* out = (float*)d_out;                // (512, 1)

    float* ws = (float*)d_ws;
    float* h1 = ws;                        // 512*512
    float* h2 = h1 + B_ * H1_;             // 512*256
    float* Mt = h2 + B_ * H2_;             // 640*512
    float* ob = Mt + NT_ * B_;             // 512*128
    float* z3 = ob + B_ * OUT_;            // 512*128

    // h1 = lrelu(x @ W1 + b1)            (512x512), K=1024, 256 blocks
    gemm_mfma<true, true, false, false><<<dim3(H1_ / 32, B_ / 32), 256, 0, stream>>>(
        x, nullptr, W1, b1, h1, B_, H1_, F_, F_);

    // h2 = lrelu(h1 @ W2 + b2)           (512x256), K=512, 128 blocks
    gemm_mfma<true, true, false, false><<<dim3(H2_ / 32, B_ / 32), 256, 0, stream>>>(
        h1, nullptr, W2, b2, h2, B_, H2_, H1_, H1_);

    // Mt = (h2 @ T)^T                    (640x512), K=256, 320 blocks
    gemm_mfma<false, false, true, false><<<dim3(NT_ / 32, B_ / 32), 256, 0, stream>>>(
        h2, nullptr, T, nullptr, Mt, B_, NT_, H2_, H2_);

    // o_b (512 x 128)
    minibatch_disc<<<256, 256, 0, stream>>>(Mt, ob);

    // z3 = lrelu(concat([h2, ob]) @ W3 + b3)   (512x128), K=384, 64 blocks
    gemm_mfma<true, true, false, true><<<dim3(OUT_ / 32, B_ / 32), 256, 0, stream>>>(
        h2, ob, W3, b3, z3, B_, OUT_, H2_ + OUT_, 0);

    // out = z3 @ W4 + b4                 (512 x 1)
    final_dot<<<B_ / 256, 256, 0, stream>>>(z3, W4, b4, out);
}

// Round 4
// 114.152 us; speedup vs baseline: 1.6740x; 1.6740x over previous
//
#include <hip/hip_runtime.h>
#include <math.h>

// Problem dims
#define B_   512
#define F_   1024
#define H1_  512
#define H2_  256
#define OUT_ 128
#define KD_  5
#define NT_  640
#define ZK_  384   // H2_ + OUT_

typedef short bf16x8 __attribute__((ext_vector_type(8)));
typedef float f32x16 __attribute__((ext_vector_type(16)));

__device__ __forceinline__ float lrelu(float v) { return v >= 0.f ? v : 0.2f * v; }

// fp32 -> bf16 round-to-nearest-even
__device__ __forceinline__ unsigned f2bf(float f) {
    unsigned u = __float_as_uint(f);
    return (u + 0x7fffu + ((u >> 16) & 1u)) >> 16;
}
__device__ __forceinline__ unsigned pack2bf(float a, float b) {
    return f2bf(a) | (f2bf(b) << 16);
}

// ---------------------------------------------------------------------------
// pack: one launch that prepares all bf16 operands.
//   blocks [0,256):        xb[512][1024] bf16 <- x (straight convert, uint4)
//   blocks [256,768):      W1t[512][1024] <- W1[1024][512]^T   (512 tiles)
//   blocks [768,896):      W2t[256][512]  <- W2[512][256]^T    (128 tiles)
//   blocks [896,1056):     Tt [640][256]  <- T [256][640]^T    (160 tiles)
//   blocks [1056,1104):    W3t[128][384]  <- W3[384][128]^T    ( 48 tiles)
// Transpose: LDS 32x33 tile, coalesced read + coalesced packed write.
// ---------------------------------------------------------------------------
#define NXB 256
#define NW1 512
#define NW2 128
#define NTT 160
#define PACK_BLOCKS (NXB + NW1 + NW2 + NTT + 48)

__global__ __launch_bounds__(256)
void pack_kernel(const float* __restrict__ x,  const float* __restrict__ W1,
                 const float* __restrict__ W2, const float* __restrict__ T,
                 const float* __restrict__ W3,
                 unsigned short* __restrict__ xb,  unsigned short* __restrict__ W1t,
                 unsigned short* __restrict__ W2t, unsigned short* __restrict__ Tt,
                 unsigned short* __restrict__ W3t)
{
    int b = blockIdx.x;
    const int t = threadIdx.x;
    if (b < NXB) {                      // x convert: 2048 elems/block, 8/thread
        const int base = b * 2048 + t * 8;
        const float4 a = *(const float4*)(x + base);
        const float4 c = *(const float4*)(x + base + 4);
        uint4 o;
        o.x = pack2bf(a.x, a.y); o.y = pack2bf(a.z, a.w);
        o.z = pack2bf(c.x, c.y); o.w = pack2bf(c.z, c.w);
        *(uint4*)(xb + base) = o;
        return;
    }
    __shared__ float Tl[32][33];
    const float* src; unsigned short* dst; int R, C, tile;
    b -= NXB;
    if (b < NW1)              { src = W1; dst = W1t; R = 1024; C = 512; tile = b; }
    else if ((b -= NW1) < NW2){ src = W2; dst = W2t; R = 512;  C = 256; tile = b; }
    else if ((b -= NW2) < NTT){ src = T;  dst = Tt;  R = 256;  C = 640; tile = b; }
    else                      { b -= NTT;  src = W3; dst = W3t; R = 384; C = 128; tile = b; }
    const int tpc = C / 32;
    const int tr = tile / tpc, tc = tile % tpc;
    {
        const int col = t & 31, rr = t >> 5;
        #pragma unroll
        for (int p = 0; p < 4; ++p)
            Tl[rr + 8 * p][col] = src[(size_t)(tr * 32 + rr + 8 * p) * C + tc * 32 + col];
    }
    __syncthreads();
    const int orow = t >> 3, up = t & 7;      // out row (= src col), uint pair
    unsigned* d = (unsigned*)(dst + (size_t)(tc * 32 + orow) * R + tr * 32);
    d[up]     = pack2bf(Tl[2 * up][orow],      Tl[2 * up + 1][orow]);
    d[up + 8] = pack2bf(Tl[2 * up + 16][orow], Tl[2 * up + 17][orow]);
}

// ---------------------------------------------------------------------------
// Barrier-free MFMA GEMM: C[M,N] = act(A @ B^T + bias)
//   A: bf16 [M][LDA] (k contiguous) ; B: bf16 [N][LDB] (k contiguous)
//   Block = WAVES waves, one 32x32 output tile; wave w owns k-slice
//   [w*KSLICE, (w+1)*KSLICE). K-loop has NO barriers and NO LDS: each MFMA
//   fragment is one dwordx4 global load (L2-resident) -> compiler pipelines.
//   One LDS reduction + epilogue at the end.
//   CONCAT_A: k<256 from A (h2b bf16, ld 256); k>=256 from obA+obB fp32
//   (two disc i-half partials, summed here).
// ---------------------------------------------------------------------------
template<int WAVES, int KSLICE, int LDA, int LDB,
         bool RELU, bool HAS_BIAS, bool BF16_OUT, bool CONCAT_A>
__global__ __launch_bounds__(WAVES * 64)
void gemm(const unsigned short* __restrict__ Ab,
          const float* __restrict__ obA, const float* __restrict__ obB,
          const unsigned short* __restrict__ Bt,
          const float* __restrict__ bias,
          void* __restrict__ Cout, int M, int N)
{
    __shared__ float Red[WAVES * 1024];
    const int tid  = threadIdx.x;
    const int wav  = tid >> 6;
    const int lane = tid & 63;
    const int half = lane >> 5;
    const int mn   = lane & 31;
    const int m0   = blockIdx.y * 32;
    const int n0   = blockIdx.x * 32;
    const int kw   = wav * KSLICE;

    f32x16 acc;
    #pragma unroll
    for (int i = 0; i < 16; ++i) acc[i] = 0.f;

    const unsigned short* arow = Ab + (size_t)(m0 + mn) * LDA;
    const unsigned short* brow = Bt + (size_t)(n0 + mn) * LDB;

    #pragma unroll
    for (int s = 0; s < KSLICE / 16; ++s) {
        const int k = kw + 16 * s + 8 * half;
        bf16x8 af, bf;
        if (CONCAT_A) {
            if (k < H2_) {
                af = *(const bf16x8*)&Ab[(size_t)(m0 + mn) * H2_ + k];
            } else {
                const float* pa = obA + (size_t)(m0 + mn) * OUT_ + (k - H2_);
                const float* pb = obB + (size_t)(m0 + mn) * OUT_ + (k - H2_);
                union { unsigned u[4]; bf16x8 v; } cv;
                #pragma unroll
                for (int jj = 0; jj < 4; ++jj)
                    cv.u[jj] = pack2bf(pa[2 * jj] + pb[2 * jj],
                                       pa[2 * jj + 1] + pb[2 * jj + 1]);
                af = cv.v;
            }
        } else {
            af = *(const bf16x8*)&arow[k];
        }
        bf = *(const bf16x8*)&brow[k];
        acc = __builtin_amdgcn_mfma_f32_32x32x16_bf16(af, bf, acc, 0, 0, 0);
    }

    // C/D layout (verified): col = lane&31, row = (reg&3) + 8*(reg>>2) + 4*(lane>>5)
    #pragma unroll
    for (int r = 0; r < 16; ++r) {
        const int row = (r & 3) + 8 * (r >> 2) + 4 * half;
        Red[wav * 1024 + row * 32 + mn] = acc[r];
    }
    __syncthreads();

    if (tid < 256) {
        const int e0 = tid * 4, row = e0 >> 5, col = e0 & 31;
        float v[4];
        #pragma unroll
        for (int q = 0; q < 4; ++q) {
            float u = 0.f;
            #pragma unroll
            for (int w = 0; w < WAVES; ++w) u += Red[w * 1024 + e0 + q];
            if (HAS_BIAS) u += bias[n0 + col + q];
            if (RELU) u = lrelu(u);
            v[q] = u;
        }
        if (BF16_OUT) {
            uint2 o;
            o.x = pack2bf(v[0], v[1]); o.y = pack2bf(v[2], v[3]);
            *(uint2*)((unsigned short*)Cout + (size_t)(m0 + row) * N + n0 + col) = o;
        } else {
            *(float4*)((float*)Cout + (size_t)(m0 + row) * N + n0 + col) =
                make_float4(v[0], v[1], v[2], v[3]);
        }
    }
}

// ---------------------------------------------------------------------------
// Minibatch discrimination, high-occupancy split.
//   Mt: fp32 [640][512], row nt = o*5+k holds M[:, o, k].
//   block = (o, j-quarter, i-half): 1024 blocks x 128 threads (8 waves/CU).
//   obH[ih][j][o] = sum_{i in half} exp(-L1(M_i, M_j)) - (self ? 1 : 0)
//   L staged as [i][8] -> inner loop = 1 ds_read_b128 + 1 b32 (broadcast).
// ---------------------------------------------------------------------------
__global__ __launch_bounds__(128)
void disc_kernel(const float* __restrict__ Mt, float* __restrict__ obH)
{
    const int o  = blockIdx.x >> 3;
    const int jq = (blockIdx.x >> 1) & 3;
    const int ih = blockIdx.x & 1;
    const int t  = threadIdx.x;
    const int j  = jq * 128 + t;
    const int i0 = ih * 256;
    __shared__ float L[256 * 8];
    const float* base = Mt + (size_t)o * 5 * 512;
    #pragma unroll
    for (int k = 0; k < KD_; ++k) {
        L[t * 8 + k]         = base[k * 512 + i0 + t];
        L[(t + 128) * 8 + k] = base[k * 512 + i0 + t + 128];
    }
    const float mj0 = base[0 * 512 + j], mj1 = base[1 * 512 + j],
                mj2 = base[2 * 512 + j], mj3 = base[3 * 512 + j],
                mj4 = base[4 * 512 + j];
    __syncthreads();

    float acc0 = 0.f, acc1 = 0.f;
    #pragma unroll 4
    for (int i = 0; i < 256; i += 2) {
        {
            const float4 a = *(const float4*)&L[i * 8];
            const float n = fabsf(a.x - mj0) + fabsf(a.y - mj1) + fabsf(a.z - mj2)
                          + fabsf(a.w - mj3) + fabsf(L[i * 8 + 4] - mj4);
            acc0 += __expf(-n);
        }
        {
            const float4 a = *(const float4*)&L[(i + 1) * 8];
            const float n = fabsf(a.x - mj0) + fabsf(a.y - mj1) + fabsf(a.z - mj2)
                          + fabsf(a.w - mj3) + fabsf(L[(i + 1) * 8 + 4] - mj4);
            acc1 += __expf(-n);
        }
    }
    const float self = ((j >> 8) == ih) ? 1.f : 0.f;
    obH[(size_t)ih * B_ * OUT_ + (size_t)j * OUT_ + o] = acc0 + acc1 - self;
}

// ---------------------------------------------------------------------------
// out[m] = dot(z3[m,:], W4) + b4 ; 4 lanes per row, shfl reduce.
// ---------------------------------------------------------------------------
__global__ __launch_bounds__(256)
void final_dot(const float* __restrict__ z3, const float* __restrict__ W4,
               const float* __restrict__ b4, float* __restrict__ out)
{
    const int t = threadIdx.x;
    const int row = blockIdx.x * 64 + (t >> 2);
    const int q = t & 3;
    const float4* z = (const float4*)(z3 + (size_t)row * OUT_ + q * 32);
    const float4* w = (const float4*)(W4 + q * 32);
    float acc = 0.f;
    #pragma unroll
    for (int k = 0; k < 8; ++k) {
        const float4 a = z[k], b = w[k];
        acc += a.x * b.x + a.y * b.y + a.z * b.z + a.w * b.w;
    }
    acc += __shfl_down(acc, 2, 4);
    acc += __shfl_down(acc, 1, 4);
    if (q == 0) out[row] = acc + b4[0];
}

extern "C" void kernel_launch(void* const* d_in, const int* in_sizes, int n_in,
                              void* d_out, int out_size, void* d_ws, size_t ws_size,
                              hipStream_t stream) {
    const float* x  = (const float*)d_in[0];
    const float* W1 = (const float*)d_in[1];
    const float* b1 = (const float*)d_in[2];
    const float* W2 = (const float*)d_in[3];
    const float* b2 = (const float*)d_in[4];
    const float* T  = (const float*)d_in[5];
    const float* W3 = (const float*)d_in[6];
    const float* b3 = (const float*)d_in[7];
    const float* W4 = (const float*)d_in[8];
    const float* b4 = (const float*)d_in[9];
    float* out = (float*)d_out;

    // Workspace layout (byte offsets, all 16B-aligned)
    char* ws = (char*)d_ws;
    float*          Mt  = (float*)(ws + 0);                 // 640*512*4   = 1310720
    float*          obH = (float*)(ws + 1310720);           // 2*512*128*4 =  524288
    float*          z3  = (float*)(ws + 1835008);           // 512*128*4   =  262144
    unsigned short* xb  = (unsigned short*)(ws + 2097152);  // 512*1024*2  = 1048576
    unsigned short* W1t = (unsigned short*)(ws + 3145728);  // 512*1024*2  = 1048576
    unsigned short* W2t = (unsigned short*)(ws + 4194304);  // 256*512*2   =  262144
    unsigned short* Tt  = (unsigned short*)(ws + 4456448);  // 640*256*2   =  327680
    unsigned short* W3t = (unsigned short*)(ws + 4784128);  // 128*384*2   =   98304
    unsigned short* h1b = (unsigned short*)(ws + 4882432);  // 512*512*2   =  524288
    unsigned short* h2b = (unsigned short*)(ws + 5406720);  // 512*256*2   =  262144
    // total 5,668,864 bytes

    // 1) pack all bf16 operands
    pack_kernel<<<PACK_BLOCKS, 256, 0, stream>>>(x, W1, W2, T, W3,
                                                 xb, W1t, W2t, Tt, W3t);

    // 2) h1 = lrelu(x @ W1 + b1)  (512x512, K=1024) -> bf16 ; 256 blocks x 8 waves
    gemm<8, 128, F_, F_, true, true, true, false>
        <<<dim3(H1_ / 32, B_ / 32), 512, 0, stream>>>(
        xb, nullptr, nullptr, W1t, b1, h1b, B_, H1_);

    // 3) h2 = lrelu(h1 @ W2 + b2) (512x256, K=512) -> bf16 ; 128 blocks x 8 waves
    gemm<8, 64, H1_, H1_, true, true, true, false>
        <<<dim3(H2_ / 32, B_ / 32), 512, 0, stream>>>(
        h1b, nullptr, nullptr, W2t, b2, h2b, B_, H2_);

    // 4) Mt = T^T @ h2^T  (640x512, K=256) -> fp32 (operand-swapped: Mt direct)
    gemm<4, 64, H2_, H2_, false, false, false, false>
        <<<dim3(B_ / 32, NT_ / 32), 256, 0, stream>>>(
        Tt, nullptr, nullptr, h2b, nullptr, Mt, NT_, B_);

    // 5) minibatch discrimination -> obH (two i-half partials)
    disc_kernel<<<1024, 128, 0, stream>>>(Mt, obH);

    // 6) z3 = lrelu(concat([h2, obA+obB]) @ W3 + b3) (512x128, K=384) -> fp32
    gemm<8, 48, H2_, ZK_, true, true, false, true>
        <<<dim3(OUT_ / 32, B_ / 32), 512, 0, stream>>>(
        h2b, obH, obH + B_ * OUT_, W3t, b3, z3, B_, OUT_);

    // 7) out = z3 @ W4 + b4
    final_dot<<<B_ / 64, 256, 0, stream>>>(z3, W4, b4, out);
}